// Round 8
// baseline (1225.899 us; speedup 1.0000x reference)
//
#include <hip/hip_runtime.h>

#define NN 100000
#define NE 1600000
#define DN 16
#define DE 8
#define H  32
#define NL 7
#define CAP 64                                   // per-node slot capacity (P(deg>64) ~ e^-40)

#define SCAN_BT   1024                           // threads per scan block
#define SCAN_NB   ((NN + SCAN_BT - 1) / SCAN_BT) // 98 blocks
#define BSUM_T    128                            // >= SCAN_NB, power of 2

// ---------------- CSR build (once per call) ----------------

__global__ __launch_bounds__(256) void zero_cnt_kernel(int* __restrict__ cnt) {
    int i = blockIdx.x * blockDim.x + threadIdx.x;
    if (i < NN) cnt[i] = 0;
}

// primary path: single atomic pass, edge index into fixed-capacity slots
__global__ __launch_bounds__(256) void slot_scatter_kernel(
        const int* __restrict__ dst, int* __restrict__ cnt,
        int* __restrict__ slots) {
    int e = blockIdx.x * blockDim.x + threadIdx.x;
    if (e >= NE) return;
    int d = dst[e];
    int pos = atomicAdd(&cnt[d], 1);
    if (pos < CAP) slots[(long)d * CAP + pos] = e;
}

// fallback path: hist (second atomic pass later)
__global__ __launch_bounds__(256) void hist_kernel(const int* __restrict__ dst,
                                                   int* __restrict__ cnt) {
    int e = blockIdx.x * blockDim.x + threadIdx.x;
    if (e < NE) atomicAdd(&cnt[dst[e]], 1);
}

// scan phase 1: per-block partial sums of min(cnt,cap)
__global__ __launch_bounds__(SCAN_BT) void scan_partial_kernel(
        const int* __restrict__ cnt, int* __restrict__ bsum, int cap) {
    __shared__ int red[SCAN_BT];
    int t = threadIdx.x;
    int i = blockIdx.x * SCAN_BT + t;
    red[t] = (i < NN) ? min(cnt[i], cap) : 0;
    __syncthreads();
    for (int off = SCAN_BT / 2; off > 0; off >>= 1) {
        if (t < off) red[t] += red[t + off];
        __syncthreads();
    }
    if (t == 0) bsum[blockIdx.x] = red[0];
}

// scan phase 2: single small block scans the 98 block sums (exclusive)
__global__ __launch_bounds__(BSUM_T) void scan_bsum_kernel(
        const int* __restrict__ bsum, int* __restrict__ boff,
        int* __restrict__ rowstart) {
    __shared__ int part[BSUM_T];
    int t = threadIdx.x;
    int v = (t < SCAN_NB) ? bsum[t] : 0;
    part[t] = v;
    __syncthreads();
    for (int off = 1; off < BSUM_T; off <<= 1) {
        int add = (t >= off) ? part[t - off] : 0;
        __syncthreads();
        part[t] += add;
        __syncthreads();
    }
    if (t < SCAN_NB) boff[t] = part[t] - v;           // exclusive
    if (t == BSUM_T - 1) rowstart[NN] = part[t];      // total
}

// scan phase 3: per-block exclusive scan + block offset -> rowstart, cursor
__global__ __launch_bounds__(SCAN_BT) void scan_final_kernel(
        const int* __restrict__ cnt, const int* __restrict__ boff,
        int* __restrict__ rowstart, int* __restrict__ cursor, int cap) {
    __shared__ int part[SCAN_BT];
    int t = threadIdx.x;
    int i = blockIdx.x * SCAN_BT + t;
    int v = (i < NN) ? min(cnt[i], cap) : 0;
    part[t] = v;
    __syncthreads();
    for (int off = 1; off < SCAN_BT; off <<= 1) {
        int add = (t >= off) ? part[t - off] : 0;
        __syncthreads();
        part[t] += add;
        __syncthreads();
    }
    if (i < NN) {
        int r = boff[blockIdx.x] + part[t] - v;       // exclusive
        rowstart[i] = r;
        cursor[i]   = r;
    }
}

// compact: slots -> dst-sorted es (src ids) and eas (edge attrs). Sequential writes.
__global__ __launch_bounds__(256) void compact_kernel(
        const int* __restrict__ slots, const int* __restrict__ rowstart,
        const int* __restrict__ src, const float* __restrict__ ea,
        int* __restrict__ es, float* __restrict__ eas) {
    int tid  = blockIdx.x * blockDim.x + threadIdx.x;
    int node = tid >> 4;
    int lane = tid & 15;
    if (node >= NN) return;
    int lo = rowstart[node];
    int deg = rowstart[node + 1] - lo;
    for (int k = lane; k < deg; k += 16) {
        int e = slots[(long)node * CAP + k];
        es[lo + k] = src[e];
        const float4* s4 = (const float4*)(ea + (long)e * DE);
        float4 a = s4[0], b = s4[1];
        float4* d4 = (float4*)(eas + (long)(lo + k) * DE);
        d4[0] = a; d4[1] = b;
    }
}

// fallback combined scatter (second atomic pass)
__global__ __launch_bounds__(256) void scatter_combined_kernel(
        const int* __restrict__ src, const int* __restrict__ dst,
        const float* __restrict__ ea,
        int* __restrict__ cursor,
        int* __restrict__ es, float* __restrict__ eas) {
    int e = blockIdx.x * blockDim.x + threadIdx.x;
    if (e >= NE) return;
    int pos = atomicAdd(&cursor[dst[e]], 1);
    es[pos] = src[e];
    const float4* s4 = (const float4*)(ea + (long)e * DE);
    float4 a = s4[0], b = s4[1];
    float4* d4 = (float4*)(eas + (long)pos * DE);
    d4[0] = a; d4[1] = b;
}

// ---------------- node init: h = x@W_node + b ; hm = h@Wm0_top + bm0 ----------------
__global__ __launch_bounds__(256) void init_kernel(
        const float* __restrict__ x,
        const float* __restrict__ W_node, const float* __restrict__ b_node,
        const float* __restrict__ Wm0, const float* __restrict__ bm0,
        float* __restrict__ h, float* __restrict__ hm)
{
    int n = blockIdx.x * blockDim.x + threadIdx.x;
    if (n >= NN) return;

    float xin[DN];
    #pragma unroll
    for (int k = 0; k < DN/4; ++k) {
        float4 v = ((const float4*)(x + (long)n*DN))[k];
        xin[4*k+0]=v.x; xin[4*k+1]=v.y; xin[4*k+2]=v.z; xin[4*k+3]=v.w;
    }
    float hv[H];
    #pragma unroll
    for (int j = 0; j < H; ++j) hv[j] = b_node[j];
    #pragma unroll
    for (int k = 0; k < DN; ++k)
        #pragma unroll
        for (int j = 0; j < H; ++j)
            hv[j] = fmaf(xin[k], W_node[k*H+j], hv[j]);

    #pragma unroll
    for (int j = 0; j < H/4; ++j)
        ((float4*)(h + (long)n*H))[j] = make_float4(hv[4*j],hv[4*j+1],hv[4*j+2],hv[4*j+3]);

    float hmv[H];
    #pragma unroll
    for (int j = 0; j < H; ++j) hmv[j] = bm0[j];
    #pragma unroll
    for (int k = 0; k < H; ++k)
        #pragma unroll
        for (int j = 0; j < H; ++j)
            hmv[j] = fmaf(hv[k], Wm0[k*H+j], hmv[j]);

    #pragma unroll
    for (int j = 0; j < H/4; ++j)
        ((float4*)(hm + (long)n*H))[j] = make_float4(hmv[4*j],hmv[4*j+1],hmv[4*j+2],hmv[4*j+3]);
}

// per-edge message + max, shared by all aggr paths
#define MSG_FMA(A, B, M0, M1)                                         \
    M0 = fmaf(A.x, w0[0], M0);  M1 = fmaf(A.x, w1[0], M1);            \
    M0 = fmaf(A.y, w0[1], M0);  M1 = fmaf(A.y, w1[1], M1);            \
    M0 = fmaf(A.z, w0[2], M0);  M1 = fmaf(A.z, w1[2], M1);            \
    M0 = fmaf(A.w, w0[3], M0);  M1 = fmaf(A.w, w1[3], M1);            \
    M0 = fmaf(B.x, w0[4], M0);  M1 = fmaf(B.x, w1[4], M1);            \
    M0 = fmaf(B.y, w0[5], M0);  M1 = fmaf(B.y, w1[5], M1);            \
    M0 = fmaf(B.z, w0[6], M0);  M1 = fmaf(B.z, w1[6], M1);            \
    M0 = fmaf(B.w, w0[7], M0);  M1 = fmaf(B.w, w1[7], M1);

// ---------------- per-layer aggregation: CSR gather-max, chunked deep-pipeline ----------
// 16 lanes per node; lane `sub` owns channels [sub*2, sub*2+2).
// Chunk of 16 edges: one coalesced es load -> shfl-broadcast -> 16 independent hm gathers
// in flight before compute. Then chunk of 8, then serial tail.
__global__ __launch_bounds__(256) void aggr_kernel(
        const int* __restrict__ rowstart, const int* __restrict__ es,
        const float* __restrict__ eas,      // [E][DE] dst-sorted
        const float* __restrict__ Wm_bot,   // [DE][H]
        const float* __restrict__ hm,
        float* __restrict__ aggr)
{
    int tid  = blockIdx.x * blockDim.x + threadIdx.x;
    int node = tid >> 4;
    int sub  = tid & 15;
    if (node >= NN) return;

    float w0[DE], w1[DE];
    #pragma unroll
    for (int k = 0; k < DE; ++k) {
        w0[k] = Wm_bot[k*H + sub*2 + 0];
        w1[k] = Wm_bot[k*H + sub*2 + 1];
    }

    float acc0 = -__builtin_inff(), acc1 = -__builtin_inff();

    int lo = rowstart[node], hi = rowstart[node+1];
    int i = lo;

    // ---- 16-edge chunks: 16 gathers in flight ----
    for (; i + 16 <= hi; i += 16) {
        int sv = es[i + sub];                       // coalesced: lane sub -> edge i+sub
        float2 hv[16];
        #pragma unroll
        for (int k = 0; k < 16; ++k) {
            int s = __shfl(sv, k, 16);
            hv[k] = *(const float2*)(hm + (long)s*H + sub*2);
        }
        #pragma unroll
        for (int k = 0; k < 16; ++k) {
            const float4* p = (const float4*)(eas + (long)(i+k) * DE);
            float4 a = p[0], b = p[1];
            float m0 = hv[k].x, m1 = hv[k].y;
            MSG_FMA(a, b, m0, m1)
            acc0 = fmaxf(acc0, m0);
            acc1 = fmaxf(acc1, m1);
        }
    }
    // ---- one 8-edge chunk ----
    if (i + 8 <= hi) {
        int sv = es[i + (sub & 7)];                 // lanes 0-7 and 8-15 mirror
        float2 hv[8];
        #pragma unroll
        for (int k = 0; k < 8; ++k) {
            int s = __shfl(sv, k, 16);              // group lane k holds es[i+k]
            hv[k] = *(const float2*)(hm + (long)s*H + sub*2);
        }
        #pragma unroll
        for (int k = 0; k < 8; ++k) {
            const float4* p = (const float4*)(eas + (long)(i+k) * DE);
            float4 a = p[0], b = p[1];
            float m0 = hv[k].x, m1 = hv[k].y;
            MSG_FMA(a, b, m0, m1)
            acc0 = fmaxf(acc0, m0);
            acc1 = fmaxf(acc1, m1);
        }
        i += 8;
    }
    // ---- serial tail (<8 edges), unrolled by 2 ----
    for (; i + 1 < hi; i += 2) {
        int s0 = es[i], s1 = es[i+1];
        const float4* p0 = (const float4*)(eas + (long)i * DE);
        const float4* p1 = (const float4*)(eas + (long)(i+1) * DE);
        float2 hv0 = *(const float2*)(hm + (long)s0*H + sub*2);
        float2 hv1 = *(const float2*)(hm + (long)s1*H + sub*2);
        float4 a0 = p0[0], b0 = p0[1];
        float4 a1 = p1[0], b1 = p1[1];
        float m00 = hv0.x, m01 = hv0.y;
        float m10 = hv1.x, m11 = hv1.y;
        MSG_FMA(a0, b0, m00, m01)
        MSG_FMA(a1, b1, m10, m11)
        acc0 = fmaxf(acc0, fmaxf(m00, m10));
        acc1 = fmaxf(acc1, fmaxf(m01, m11));
    }
    if (i < hi) {
        int s0 = es[i];
        const float4* p0 = (const float4*)(eas + (long)i * DE);
        float2 hv0 = *(const float2*)(hm + (long)s0*H + sub*2);
        float4 a0 = p0[0], b0 = p0[1];
        float m00 = hv0.x, m01 = hv0.y;
        MSG_FMA(a0, b0, m00, m01)
        acc0 = fmaxf(acc0, m00);
        acc1 = fmaxf(acc1, m01);
    }
    if (lo == hi) { acc0 = 0.f; acc1 = 0.f; }
    *(float2*)(aggr + (long)node*H + sub*2) = make_float2(acc0, acc1);
}

// ---------------- node update: relu(aggr@Wu+bu) + residual ; next hm or post ----------------
__global__ __launch_bounds__(256) void update_kernel(
        const float* __restrict__ Wu, const float* __restrict__ bu,
        const float* __restrict__ Wm_next, const float* __restrict__ bm_next, // null if last
        const float* __restrict__ W_post, const float* __restrict__ b_post,   // used if last
        float* __restrict__ h, float* __restrict__ hm,
        const float* __restrict__ aggr, float* __restrict__ out, int last)
{
    int n = blockIdx.x * blockDim.x + threadIdx.x;
    if (n >= NN) return;

    float av[H];
    #pragma unroll
    for (int j = 0; j < H/4; ++j) {
        float4 v = ((const float4*)(aggr + (long)n*H))[j];
        av[4*j+0]=v.x; av[4*j+1]=v.y; av[4*j+2]=v.z; av[4*j+3]=v.w;
    }

    float uv[H];
    #pragma unroll
    for (int j = 0; j < H; ++j) uv[j] = bu[j];
    #pragma unroll
    for (int k = 0; k < H; ++k)
        #pragma unroll
        for (int j = 0; j < H; ++j)
            uv[j] = fmaf(av[k], Wu[k*H+j], uv[j]);

    float hv[H];
    #pragma unroll
    for (int j = 0; j < H/4; ++j) {
        float4 v = ((const float4*)(h + (long)n*H))[j];
        hv[4*j+0]=v.x; hv[4*j+1]=v.y; hv[4*j+2]=v.z; hv[4*j+3]=v.w;
    }
    #pragma unroll
    for (int j = 0; j < H; ++j) hv[j] += fmaxf(uv[j], 0.f);

    #pragma unroll
    for (int j = 0; j < H/4; ++j)
        ((float4*)(h + (long)n*H))[j] = make_float4(hv[4*j],hv[4*j+1],hv[4*j+2],hv[4*j+3]);

    if (!last) {
        float hmv[H];
        #pragma unroll
        for (int j = 0; j < H; ++j) hmv[j] = bm_next[j];
        #pragma unroll
        for (int k = 0; k < H; ++k)
            #pragma unroll
            for (int j = 0; j < H; ++j)
                hmv[j] = fmaf(hv[k], Wm_next[k*H+j], hmv[j]);
        #pragma unroll
        for (int j = 0; j < H/4; ++j)
            ((float4*)(hm + (long)n*H))[j] = make_float4(hmv[4*j],hmv[4*j+1],hmv[4*j+2],hmv[4*j+3]);
    } else {
        float acc = b_post[0];
        #pragma unroll
        for (int k = 0; k < H; ++k) acc = fmaf(hv[k], W_post[k], acc);
        out[n] = acc;
    }
}

extern "C" void kernel_launch(void* const* d_in, const int* in_sizes, int n_in,
                              void* d_out, int out_size, void* d_ws, size_t ws_size,
                              hipStream_t stream)
{
    const float* x         = (const float*)d_in[0];
    const float* edge_attr = (const float*)d_in[1];
    const int*   edge_index= (const int*)  d_in[2];
    const float* W_node    = (const float*)d_in[3];
    const float* b_node    = (const float*)d_in[4];
    const float* Wm        = (const float*)d_in[5];   // [L][H+DE][H]
    const float* bm        = (const float*)d_in[6];   // [L][H]
    const float* Wu        = (const float*)d_in[7];   // [L][H][H]
    const float* bu        = (const float*)d_in[8];   // [L][H]
    const float* W_post    = (const float*)d_in[9];   // [H][1]
    const float* b_post    = (const float*)d_in[10];  // [1]
    float* out = (float*)d_out;

    const int* src = edge_index;        // row 0 (x_j source)
    const int* dst = edge_index + NE;   // row 1 (aggregation target)

    // workspace layout (all 16B-aligned)
    char* ws = (char*)d_ws;
    size_t off = 0;
    float* h        = (float*)(ws + off); off += (size_t)NN*H*4;        // 12.8 MB
    float* hm       = (float*)(ws + off); off += (size_t)NN*H*4;        // 12.8 MB
    float* aggr     = (float*)(ws + off); off += (size_t)NN*H*4;        // 12.8 MB
    int*   cnt      = (int*)  (ws + off); off += (size_t)NN*4;          // 0.4 MB
    int*   rowstart = (int*)  (ws + off); off += (size_t)(NN+16)*4;     // 0.4 MB
    int*   cursor   = (int*)  (ws + off); off += (size_t)NN*4;          // 0.4 MB
    int*   bsum     = (int*)  (ws + off); off += (size_t)256*4;
    int*   boff     = (int*)  (ws + off); off += (size_t)256*4;
    int*   es       = (int*)  (ws + off); off += (size_t)NE*4;          // 6.4 MB
    float* eas      = (float*)(ws + off); off += (size_t)NE*DE*4;       // 51.2 MB
    size_t slots_off = off;
    int*   slots    = (int*)  (ws + slots_off);                          // 25.6 MB (optional)
    const int use_slots = (ws_size >= slots_off + (size_t)NN*CAP*4);

    const int nodeBlocks  = (NN + 255) / 256;
    const int edgeBlocks  = (NE + 255) / 256;
    const int aggrBlocks  = (NN*16 + 255) / 256;

    // ---- build CSR (dst-sorted edge data) ----
    zero_cnt_kernel<<<nodeBlocks, 256, 0, stream>>>(cnt);
    if (use_slots) {
        // one atomic pass
        slot_scatter_kernel<<<edgeBlocks, 256, 0, stream>>>(dst, cnt, slots);
        scan_partial_kernel<<<SCAN_NB, SCAN_BT, 0, stream>>>(cnt, bsum, CAP);
        scan_bsum_kernel<<<1, BSUM_T, 0, stream>>>(bsum, boff, rowstart);
        scan_final_kernel<<<SCAN_NB, SCAN_BT, 0, stream>>>(cnt, boff, rowstart, cursor, CAP);
        compact_kernel<<<aggrBlocks, 256, 0, stream>>>(slots, rowstart, src, edge_attr, es, eas);
    } else {
        // two atomic passes (round-5 path)
        hist_kernel<<<edgeBlocks, 256, 0, stream>>>(dst, cnt);
        scan_partial_kernel<<<SCAN_NB, SCAN_BT, 0, stream>>>(cnt, bsum, 0x7FFFFFFF);
        scan_bsum_kernel<<<1, BSUM_T, 0, stream>>>(bsum, boff, rowstart);
        scan_final_kernel<<<SCAN_NB, SCAN_BT, 0, stream>>>(cnt, boff, rowstart, cursor, 0x7FFFFFFF);
        scatter_combined_kernel<<<edgeBlocks, 256, 0, stream>>>(src, dst, edge_attr,
                                                                cursor, es, eas);
    }

    // ---- node init ----
    init_kernel<<<nodeBlocks, 256, 0, stream>>>(x, W_node, b_node, Wm, bm, h, hm);

    // ---- layers ----
    for (int l = 0; l < NL; ++l) {
        const float* Wm_l   = Wm + (size_t)l*(H+DE)*H;
        const float* Wm_bot = Wm_l + (size_t)H*H;        // rows 32..39 multiply edge_attr
        const float* Wu_l   = Wu + (size_t)l*H*H;
        const float* bu_l   = bu + (size_t)l*H;
        int last = (l == NL-1);
        const float* Wm_next = last ? nullptr : Wm + (size_t)(l+1)*(H+DE)*H;
        const float* bm_next = last ? nullptr : bm + (size_t)(l+1)*H;

        aggr_kernel<<<aggrBlocks, 256, 0, stream>>>(rowstart, es, eas, Wm_bot, hm, aggr);
        update_kernel<<<nodeBlocks, 256, 0, stream>>>(Wu_l, bu_l, Wm_next, bm_next,
                                                      W_post, b_post, h, hm, aggr, out, last);
    }
}

// Round 9
// 974.862 us; speedup vs baseline: 1.2575x; 1.2575x over previous
//
#include <hip/hip_runtime.h>

#define NN 100000
#define NE 1600000
#define DN 16
#define DE 8
#define H  32
#define NL 7
#define CAP 64                                   // per-node slot capacity (P(deg>64) negligible)

#define SCAN_BT   1024                           // threads per scan block
#define SCAN_NB   ((NN + SCAN_BT - 1) / SCAN_BT) // 98 blocks
#define BSUM_T    128                            // >= SCAN_NB, power of 2

// ---------------- CSR build (once per call) ----------------

__global__ __launch_bounds__(256) void zero_cnt_kernel(int* __restrict__ cnt) {
    int i = blockIdx.x * blockDim.x + threadIdx.x;
    if (i < NN) cnt[i] = 0;
}

// primary path: single atomic pass, edge index into fixed-capacity slots
__global__ __launch_bounds__(256) void slot_scatter_kernel(
        const int* __restrict__ dst, int* __restrict__ cnt,
        int* __restrict__ slots) {
    int e = blockIdx.x * blockDim.x + threadIdx.x;
    if (e >= NE) return;
    int d = dst[e];
    int pos = atomicAdd(&cnt[d], 1);
    if (pos < CAP) slots[(long)d * CAP + pos] = e;
}

// fallback path: hist (second atomic pass later)
__global__ __launch_bounds__(256) void hist_kernel(const int* __restrict__ dst,
                                                   int* __restrict__ cnt) {
    int e = blockIdx.x * blockDim.x + threadIdx.x;
    if (e < NE) atomicAdd(&cnt[dst[e]], 1);
}

// scan phase 1: per-block partial sums of min(cnt,cap)
__global__ __launch_bounds__(SCAN_BT) void scan_partial_kernel(
        const int* __restrict__ cnt, int* __restrict__ bsum, int cap) {
    __shared__ int red[SCAN_BT];
    int t = threadIdx.x;
    int i = blockIdx.x * SCAN_BT + t;
    red[t] = (i < NN) ? min(cnt[i], cap) : 0;
    __syncthreads();
    for (int off = SCAN_BT / 2; off > 0; off >>= 1) {
        if (t < off) red[t] += red[t + off];
        __syncthreads();
    }
    if (t == 0) bsum[blockIdx.x] = red[0];
}

// scan phase 2: single small block scans the 98 block sums (exclusive)
__global__ __launch_bounds__(BSUM_T) void scan_bsum_kernel(
        const int* __restrict__ bsum, int* __restrict__ boff,
        int* __restrict__ rowstart) {
    __shared__ int part[BSUM_T];
    int t = threadIdx.x;
    int v = (t < SCAN_NB) ? bsum[t] : 0;
    part[t] = v;
    __syncthreads();
    for (int off = 1; off < BSUM_T; off <<= 1) {
        int add = (t >= off) ? part[t - off] : 0;
        __syncthreads();
        part[t] += add;
        __syncthreads();
    }
    if (t < SCAN_NB) boff[t] = part[t] - v;           // exclusive
    if (t == BSUM_T - 1) rowstart[NN] = part[t];      // total
}

// scan phase 3: per-block exclusive scan + block offset -> rowstart, cursor
__global__ __launch_bounds__(SCAN_BT) void scan_final_kernel(
        const int* __restrict__ cnt, const int* __restrict__ boff,
        int* __restrict__ rowstart, int* __restrict__ cursor, int cap) {
    __shared__ int part[SCAN_BT];
    int t = threadIdx.x;
    int i = blockIdx.x * SCAN_BT + t;
    int v = (i < NN) ? min(cnt[i], cap) : 0;
    part[t] = v;
    __syncthreads();
    for (int off = 1; off < SCAN_BT; off <<= 1) {
        int add = (t >= off) ? part[t - off] : 0;
        __syncthreads();
        part[t] += add;
        __syncthreads();
    }
    if (i < NN) {
        int r = boff[blockIdx.x] + part[t] - v;       // exclusive
        rowstart[i] = r;
        cursor[i]   = r;
    }
}

// compact: slots -> dst-sorted es (src ids) and eas (edge attrs). Sequential writes.
__global__ __launch_bounds__(256) void compact_kernel(
        const int* __restrict__ slots, const int* __restrict__ rowstart,
        const int* __restrict__ src, const float* __restrict__ ea,
        int* __restrict__ es, float* __restrict__ eas) {
    int tid  = blockIdx.x * blockDim.x + threadIdx.x;
    int node = tid >> 4;
    int lane = tid & 15;
    if (node >= NN) return;
    int lo = rowstart[node];
    int deg = rowstart[node + 1] - lo;
    for (int k = lane; k < deg; k += 16) {
        int e = slots[(long)node * CAP + k];
        es[lo + k] = src[e];
        const float4* s4 = (const float4*)(ea + (long)e * DE);
        float4 a = s4[0], b = s4[1];
        float4* d4 = (float4*)(eas + (long)(lo + k) * DE);
        d4[0] = a; d4[1] = b;
    }
}

// fallback combined scatter (second atomic pass)
__global__ __launch_bounds__(256) void scatter_combined_kernel(
        const int* __restrict__ src, const int* __restrict__ dst,
        const float* __restrict__ ea,
        int* __restrict__ cursor,
        int* __restrict__ es, float* __restrict__ eas) {
    int e = blockIdx.x * blockDim.x + threadIdx.x;
    if (e >= NE) return;
    int pos = atomicAdd(&cursor[dst[e]], 1);
    es[pos] = src[e];
    const float4* s4 = (const float4*)(ea + (long)e * DE);
    float4 a = s4[0], b = s4[1];
    float4* d4 = (float4*)(eas + (long)pos * DE);
    d4[0] = a; d4[1] = b;
}

// ---------------- node init: h = x@W_node + b ; hm = h@Wm0_top + bm0 ----------------
__global__ __launch_bounds__(256) void init_kernel(
        const float* __restrict__ x,
        const float* __restrict__ W_node, const float* __restrict__ b_node,
        const float* __restrict__ Wm0, const float* __restrict__ bm0,
        float* __restrict__ h, float* __restrict__ hm)
{
    int n = blockIdx.x * blockDim.x + threadIdx.x;
    if (n >= NN) return;

    float xin[DN];
    #pragma unroll
    for (int k = 0; k < DN/4; ++k) {
        float4 v = ((const float4*)(x + (long)n*DN))[k];
        xin[4*k+0]=v.x; xin[4*k+1]=v.y; xin[4*k+2]=v.z; xin[4*k+3]=v.w;
    }
    float hv[H];
    #pragma unroll
    for (int j = 0; j < H; ++j) hv[j] = b_node[j];
    #pragma unroll
    for (int k = 0; k < DN; ++k)
        #pragma unroll
        for (int j = 0; j < H; ++j)
            hv[j] = fmaf(xin[k], W_node[k*H+j], hv[j]);

    #pragma unroll
    for (int j = 0; j < H/4; ++j)
        ((float4*)(h + (long)n*H))[j] = make_float4(hv[4*j],hv[4*j+1],hv[4*j+2],hv[4*j+3]);

    float hmv[H];
    #pragma unroll
    for (int j = 0; j < H; ++j) hmv[j] = bm0[j];
    #pragma unroll
    for (int k = 0; k < H; ++k)
        #pragma unroll
        for (int j = 0; j < H; ++j)
            hmv[j] = fmaf(hv[k], Wm0[k*H+j], hmv[j]);

    #pragma unroll
    for (int j = 0; j < H/4; ++j)
        ((float4*)(hm + (long)n*H))[j] = make_float4(hmv[4*j],hmv[4*j+1],hmv[4*j+2],hmv[4*j+3]);
}

// per-edge message + max, shared by all aggr paths
#define MSG_FMA(A, B, M0, M1)                                         \
    M0 = fmaf(A.x, w0[0], M0);  M1 = fmaf(A.x, w1[0], M1);            \
    M0 = fmaf(A.y, w0[1], M0);  M1 = fmaf(A.y, w1[1], M1);            \
    M0 = fmaf(A.z, w0[2], M0);  M1 = fmaf(A.z, w1[2], M1);            \
    M0 = fmaf(A.w, w0[3], M0);  M1 = fmaf(A.w, w1[3], M1);            \
    M0 = fmaf(B.x, w0[4], M0);  M1 = fmaf(B.x, w1[4], M1);            \
    M0 = fmaf(B.y, w0[5], M0);  M1 = fmaf(B.y, w1[5], M1);            \
    M0 = fmaf(B.z, w0[6], M0);  M1 = fmaf(B.z, w1[6], M1);            \
    M0 = fmaf(B.w, w0[7], M0);  M1 = fmaf(B.w, w1[7], M1);

// ---------------- per-layer aggregation: CSR gather-max, no atomics, unroll-4 ----------
// 16 lanes per node; lane `sub` owns channels [sub*2, sub*2+2).
// 4 independent edge chains per iteration: direct broadcast es loads (no shfl in the
// address path), 4 hm gathers + 8 eas reads in flight before compute.
__global__ __launch_bounds__(256) void aggr_kernel(
        const int* __restrict__ rowstart, const int* __restrict__ es,
        const float* __restrict__ eas,      // [E][DE] dst-sorted
        const float* __restrict__ Wm_bot,   // [DE][H]
        const float* __restrict__ hm,
        float* __restrict__ aggr)
{
    int tid  = blockIdx.x * blockDim.x + threadIdx.x;
    int node = tid >> 4;
    int sub  = tid & 15;
    if (node >= NN) return;

    float w0[DE], w1[DE];
    #pragma unroll
    for (int k = 0; k < DE; ++k) {
        w0[k] = Wm_bot[k*H + sub*2 + 0];
        w1[k] = Wm_bot[k*H + sub*2 + 1];
    }

    float acc0 = -__builtin_inff(), acc1 = -__builtin_inff();

    int lo = rowstart[node], hi = rowstart[node+1];
    int i = lo;

    // ---- unroll-4 main loop: 4 independent gather+compute chains ----
    for (; i + 3 < hi; i += 4) {
        int s0 = es[i], s1 = es[i+1], s2 = es[i+2], s3 = es[i+3];
        float2 hv0 = *(const float2*)(hm + (long)s0*H + sub*2);
        float2 hv1 = *(const float2*)(hm + (long)s1*H + sub*2);
        float2 hv2 = *(const float2*)(hm + (long)s2*H + sub*2);
        float2 hv3 = *(const float2*)(hm + (long)s3*H + sub*2);
        const float4* p0 = (const float4*)(eas + (long)i * DE);
        const float4* p1 = (const float4*)(eas + (long)(i+1) * DE);
        const float4* p2 = (const float4*)(eas + (long)(i+2) * DE);
        const float4* p3 = (const float4*)(eas + (long)(i+3) * DE);
        float4 a0 = p0[0], b0 = p0[1];
        float4 a1 = p1[0], b1 = p1[1];
        float4 a2 = p2[0], b2 = p2[1];
        float4 a3 = p3[0], b3 = p3[1];
        float m00 = hv0.x, m01 = hv0.y;
        float m10 = hv1.x, m11 = hv1.y;
        float m20 = hv2.x, m21 = hv2.y;
        float m30 = hv3.x, m31 = hv3.y;
        MSG_FMA(a0, b0, m00, m01)
        MSG_FMA(a1, b1, m10, m11)
        MSG_FMA(a2, b2, m20, m21)
        MSG_FMA(a3, b3, m30, m31)
        acc0 = fmaxf(acc0, fmaxf(fmaxf(m00, m10), fmaxf(m20, m30)));
        acc1 = fmaxf(acc1, fmaxf(fmaxf(m01, m11), fmaxf(m21, m31)));
    }
    // ---- unroll-2 ----
    for (; i + 1 < hi; i += 2) {
        int s0 = es[i], s1 = es[i+1];
        float2 hv0 = *(const float2*)(hm + (long)s0*H + sub*2);
        float2 hv1 = *(const float2*)(hm + (long)s1*H + sub*2);
        const float4* p0 = (const float4*)(eas + (long)i * DE);
        const float4* p1 = (const float4*)(eas + (long)(i+1) * DE);
        float4 a0 = p0[0], b0 = p0[1];
        float4 a1 = p1[0], b1 = p1[1];
        float m00 = hv0.x, m01 = hv0.y;
        float m10 = hv1.x, m11 = hv1.y;
        MSG_FMA(a0, b0, m00, m01)
        MSG_FMA(a1, b1, m10, m11)
        acc0 = fmaxf(acc0, fmaxf(m00, m10));
        acc1 = fmaxf(acc1, fmaxf(m01, m11));
    }
    if (i < hi) {
        int s0 = es[i];
        float2 hv0 = *(const float2*)(hm + (long)s0*H + sub*2);
        const float4* p0 = (const float4*)(eas + (long)i * DE);
        float4 a0 = p0[0], b0 = p0[1];
        float m00 = hv0.x, m01 = hv0.y;
        MSG_FMA(a0, b0, m00, m01)
        acc0 = fmaxf(acc0, m00);
        acc1 = fmaxf(acc1, m01);
    }
    if (lo == hi) { acc0 = 0.f; acc1 = 0.f; }
    *(float2*)(aggr + (long)node*H + sub*2) = make_float2(acc0, acc1);
}

// ---------------- node update: relu(aggr@Wu+bu) + residual ; next hm or post ----------------
__global__ __launch_bounds__(256) void update_kernel(
        const float* __restrict__ Wu, const float* __restrict__ bu,
        const float* __restrict__ Wm_next, const float* __restrict__ bm_next, // null if last
        const float* __restrict__ W_post, const float* __restrict__ b_post,   // used if last
        float* __restrict__ h, float* __restrict__ hm,
        const float* __restrict__ aggr, float* __restrict__ out, int last)
{
    int n = blockIdx.x * blockDim.x + threadIdx.x;
    if (n >= NN) return;

    float av[H];
    #pragma unroll
    for (int j = 0; j < H/4; ++j) {
        float4 v = ((const float4*)(aggr + (long)n*H))[j];
        av[4*j+0]=v.x; av[4*j+1]=v.y; av[4*j+2]=v.z; av[4*j+3]=v.w;
    }

    float uv[H];
    #pragma unroll
    for (int j = 0; j < H; ++j) uv[j] = bu[j];
    #pragma unroll
    for (int k = 0; k < H; ++k)
        #pragma unroll
        for (int j = 0; j < H; ++j)
            uv[j] = fmaf(av[k], Wu[k*H+j], uv[j]);

    float hv[H];
    #pragma unroll
    for (int j = 0; j < H/4; ++j) {
        float4 v = ((const float4*)(h + (long)n*H))[j];
        hv[4*j+0]=v.x; hv[4*j+1]=v.y; hv[4*j+2]=v.z; hv[4*j+3]=v.w;
    }
    #pragma unroll
    for (int j = 0; j < H; ++j) hv[j] += fmaxf(uv[j], 0.f);

    #pragma unroll
    for (int j = 0; j < H/4; ++j)
        ((float4*)(h + (long)n*H))[j] = make_float4(hv[4*j],hv[4*j+1],hv[4*j+2],hv[4*j+3]);

    if (!last) {
        float hmv[H];
        #pragma unroll
        for (int j = 0; j < H; ++j) hmv[j] = bm_next[j];
        #pragma unroll
        for (int k = 0; k < H; ++k)
            #pragma unroll
            for (int j = 0; j < H; ++j)
                hmv[j] = fmaf(hv[k], Wm_next[k*H+j], hmv[j]);
        #pragma unroll
        for (int j = 0; j < H/4; ++j)
            ((float4*)(hm + (long)n*H))[j] = make_float4(hmv[4*j],hmv[4*j+1],hmv[4*j+2],hmv[4*j+3]);
    } else {
        float acc = b_post[0];
        #pragma unroll
        for (int k = 0; k < H; ++k) acc = fmaf(hv[k], W_post[k], acc);
        out[n] = acc;
    }
}

extern "C" void kernel_launch(void* const* d_in, const int* in_sizes, int n_in,
                              void* d_out, int out_size, void* d_ws, size_t ws_size,
                              hipStream_t stream)
{
    const float* x         = (const float*)d_in[0];
    const float* edge_attr = (const float*)d_in[1];
    const int*   edge_index= (const int*)  d_in[2];
    const float* W_node    = (const float*)d_in[3];
    const float* b_node    = (const float*)d_in[4];
    const float* Wm        = (const float*)d_in[5];   // [L][H+DE][H]
    const float* bm        = (const float*)d_in[6];   // [L][H]
    const float* Wu        = (const float*)d_in[7];   // [L][H][H]
    const float* bu        = (const float*)d_in[8];   // [L][H]
    const float* W_post    = (const float*)d_in[9];   // [H][1]
    const float* b_post    = (const float*)d_in[10];  // [1]
    float* out = (float*)d_out;

    const int* src = edge_index;        // row 0 (x_j source)
    const int* dst = edge_index + NE;   // row 1 (aggregation target)

    // workspace layout (all 16B-aligned)
    char* ws = (char*)d_ws;
    size_t off = 0;
    float* h        = (float*)(ws + off); off += (size_t)NN*H*4;        // 12.8 MB
    float* hm       = (float*)(ws + off); off += (size_t)NN*H*4;        // 12.8 MB
    float* aggr     = (float*)(ws + off); off += (size_t)NN*H*4;        // 12.8 MB
    int*   cnt      = (int*)  (ws + off); off += (size_t)NN*4;          // 0.4 MB
    int*   rowstart = (int*)  (ws + off); off += (size_t)(NN+16)*4;     // 0.4 MB
    int*   cursor   = (int*)  (ws + off); off += (size_t)NN*4;          // 0.4 MB
    int*   bsum     = (int*)  (ws + off); off += (size_t)256*4;
    int*   boff     = (int*)  (ws + off); off += (size_t)256*4;
    int*   es       = (int*)  (ws + off); off += (size_t)NE*4;          // 6.4 MB
    float* eas      = (float*)(ws + off); off += (size_t)NE*DE*4;       // 51.2 MB
    size_t slots_off = off;
    int*   slots    = (int*)  (ws + slots_off);                          // 25.6 MB (optional)
    const int use_slots = (ws_size >= slots_off + (size_t)NN*CAP*4);

    const int nodeBlocks  = (NN + 255) / 256;
    const int edgeBlocks  = (NE + 255) / 256;
    const int aggrBlocks  = (NN*16 + 255) / 256;

    // ---- build CSR (dst-sorted edge data) ----
    zero_cnt_kernel<<<nodeBlocks, 256, 0, stream>>>(cnt);
    if (use_slots) {
        // one atomic pass
        slot_scatter_kernel<<<edgeBlocks, 256, 0, stream>>>(dst, cnt, slots);
        scan_partial_kernel<<<SCAN_NB, SCAN_BT, 0, stream>>>(cnt, bsum, CAP);
        scan_bsum_kernel<<<1, BSUM_T, 0, stream>>>(bsum, boff, rowstart);
        scan_final_kernel<<<SCAN_NB, SCAN_BT, 0, stream>>>(cnt, boff, rowstart, cursor, CAP);
        compact_kernel<<<aggrBlocks, 256, 0, stream>>>(slots, rowstart, src, edge_attr, es, eas);
    } else {
        // two atomic passes (round-5 path)
        hist_kernel<<<edgeBlocks, 256, 0, stream>>>(dst, cnt);
        scan_partial_kernel<<<SCAN_NB, SCAN_BT, 0, stream>>>(cnt, bsum, 0x7FFFFFFF);
        scan_bsum_kernel<<<1, BSUM_T, 0, stream>>>(bsum, boff, rowstart);
        scan_final_kernel<<<SCAN_NB, SCAN_BT, 0, stream>>>(cnt, boff, rowstart, cursor, 0x7FFFFFFF);
        scatter_combined_kernel<<<edgeBlocks, 256, 0, stream>>>(src, dst, edge_attr,
                                                                cursor, es, eas);
    }

    // ---- node init ----
    init_kernel<<<nodeBlocks, 256, 0, stream>>>(x, W_node, b_node, Wm, bm, h, hm);

    // ---- layers ----
    for (int l = 0; l < NL; ++l) {
        const float* Wm_l   = Wm + (size_t)l*(H+DE)*H;
        const float* Wm_bot = Wm_l + (size_t)H*H;        // rows 32..39 multiply edge_attr
        const float* Wu_l   = Wu + (size_t)l*H*H;
        const float* bu_l   = bu + (size_t)l*H;
        int last = (l == NL-1);
        const float* Wm_next = last ? nullptr : Wm + (size_t)(l+1)*(H+DE)*H;
        const float* bm_next = last ? nullptr : bm + (size_t)(l+1)*H;

        aggr_kernel<<<aggrBlocks, 256, 0, stream>>>(rowstart, es, eas, Wm_bot, hm, aggr);
        update_kernel<<<nodeBlocks, 256, 0, stream>>>(Wu_l, bu_l, Wm_next, bm_next,
                                                      W_post, b_post, h, hm, aggr, out, last);
    }
}

// Round 10
// 885.115 us; speedup vs baseline: 1.3850x; 1.1014x over previous
//
#include <hip/hip_runtime.h>

#define NN 100000
#define NE 1600000
#define DN 16
#define DE 8
#define H  32
#define NL 7

// ---- two-level LDS counting sort params ----
#define NBKT  ((NN + 127) >> 7)                 // 782 coarse buckets (dst>>7, 128 nodes each)
#define CBLK  256                               // blocks in coarse phases
#define EPB   ((NE + CBLK - 1) / CBLK)          // 6250 edges per coarse block
#define GCN   (NBKT * CBLK)                     // 200192 (bucket-major counts)
#define G_BT  1024
#define G_NB  ((GCN + G_BT - 1) / G_BT)         // 196 scan blocks
#define G_BSUM_T 256                            // >= G_NB

// ---------------- CSR build: no global atomics ----------------

// phase A: per-block LDS histogram of coarse buckets -> gcountsT[bkt*CBLK + blk]
__global__ __launch_bounds__(256) void coarse_hist_kernel(
        const int* __restrict__ dst, int* __restrict__ gcountsT) {
    __shared__ int hist[NBKT];
    int blk = blockIdx.x, t = threadIdx.x;
    for (int i = t; i < NBKT; i += 256) hist[i] = 0;
    __syncthreads();
    int lo = blk * EPB, hi = min(lo + EPB, NE);
    for (int i = lo + t; i < hi; i += 256)
        atomicAdd(&hist[dst[i] >> 7], 1);
    __syncthreads();
    for (int i = t; i < NBKT; i += 256)
        gcountsT[i * CBLK + blk] = hist[i];
}

// scan phase 1: per-block partial sums
__global__ __launch_bounds__(G_BT) void scanG_partial_kernel(
        const int* __restrict__ in, int* __restrict__ bsum) {
    __shared__ int red[G_BT];
    int t = threadIdx.x;
    int i = blockIdx.x * G_BT + t;
    red[t] = (i < GCN) ? in[i] : 0;
    __syncthreads();
    for (int off = G_BT / 2; off > 0; off >>= 1) {
        if (t < off) red[t] += red[t + off];
        __syncthreads();
    }
    if (t == 0) bsum[blockIdx.x] = red[0];
}

// scan phase 2: single block scans G_NB block sums (exclusive)
__global__ __launch_bounds__(G_BSUM_T) void scanG_bsum_kernel(
        const int* __restrict__ bsum, int* __restrict__ boff) {
    __shared__ int part[G_BSUM_T];
    int t = threadIdx.x;
    int v = (t < G_NB) ? bsum[t] : 0;
    part[t] = v;
    __syncthreads();
    for (int off = 1; off < G_BSUM_T; off <<= 1) {
        int add = (t >= off) ? part[t - off] : 0;
        __syncthreads();
        part[t] += add;
        __syncthreads();
    }
    if (t < G_NB) boff[t] = part[t] - v;          // exclusive
}

// scan phase 3: per-block exclusive scan + offset -> gbaseT
__global__ __launch_bounds__(G_BT) void scanG_final_kernel(
        const int* __restrict__ in, const int* __restrict__ boff,
        int* __restrict__ out) {
    __shared__ int part[G_BT];
    int t = threadIdx.x;
    int i = blockIdx.x * G_BT + t;
    int v = (i < GCN) ? in[i] : 0;
    part[t] = v;
    __syncthreads();
    for (int off = 1; off < G_BT; off <<= 1) {
        int add = (t >= off) ? part[t - off] : 0;
        __syncthreads();
        part[t] += add;
        __syncthreads();
    }
    if (i < GCN) out[i] = boff[blockIdx.x] + part[t] - v;   // exclusive
}

// phase C: scatter edges into coarse-bucketed order using LDS cursors (no global atomics)
__global__ __launch_bounds__(256) void coarse_scatter_kernel(
        const int* __restrict__ dst, const int* __restrict__ gbaseT,
        int2* __restrict__ ebkt) {
    __shared__ int base[NBKT];
    int blk = blockIdx.x, t = threadIdx.x;
    for (int i = t; i < NBKT; i += 256)
        base[i] = gbaseT[i * CBLK + blk];
    __syncthreads();
    int lo = blk * EPB, hi = min(lo + EPB, NE);
    for (int i = lo + t; i < hi; i += 256) {
        int d = dst[i];
        int pos = atomicAdd(&base[d >> 7], 1);    // LDS atomic
        ebkt[pos] = make_int2(i, d);
    }
}

// phase D: per-bucket fine sort (128 nodes) -> rowstart + compacted es/eas
__global__ __launch_bounds__(256) void fine_sort_kernel(
        const int2* __restrict__ ebkt, const int* __restrict__ gbaseT,
        const int* __restrict__ src, const float* __restrict__ ea,
        int* __restrict__ rowstart, int* __restrict__ es, float* __restrict__ eas) {
    __shared__ int s_hist[128], s_incl[128], s_cur[128];
    int b = blockIdx.x, t = threadIdx.x;
    int segstart = gbaseT[b * CBLK];
    int segend   = (b == NBKT - 1) ? NE : gbaseT[(b + 1) * CBLK];

    if (t < 128) { s_hist[t] = 0; s_cur[t] = 0; }
    __syncthreads();
    for (int i = segstart + t; i < segend; i += 256)
        atomicAdd(&s_hist[ebkt[i].y & 127], 1);
    __syncthreads();
    // Hillis-Steele inclusive scan over 128 (threads 0..127; all threads hit syncs)
    if (t < 128) s_incl[t] = s_hist[t];
    __syncthreads();
    for (int off = 1; off < 128; off <<= 1) {
        int add = (t < 128 && t >= off) ? s_incl[t - off] : 0;
        __syncthreads();
        if (t < 128) s_incl[t] += add;
        __syncthreads();
    }
    // rowstart for this bucket's nodes (exclusive = incl - hist)
    if (t < 128) {
        int node = b * 128 + t;
        if (node < NN) rowstart[node] = segstart + s_incl[t] - s_hist[t];
    }
    if (b == NBKT - 1 && t == 0) rowstart[NN] = NE;
    __syncthreads();
    // pass 2: place each edge, copy payload sequentially within node runs
    for (int i = segstart + t; i < segend; i += 256) {
        int2 ed = ebkt[i];
        int j = ed.y & 127;
        int lp = atomicAdd(&s_cur[j], 1);         // LDS atomic
        int pos = segstart + (s_incl[j] - s_hist[j]) + lp;
        int e = ed.x;
        es[pos] = src[e];
        const float4* s4 = (const float4*)(ea + (long)e * DE);
        float4 a = s4[0], bb = s4[1];
        float4* d4 = (float4*)(eas + (long)pos * DE);
        d4[0] = a; d4[1] = bb;
    }
}

// ---------------- node init: h = x@W_node + b ; hm = h@Wm0_top + bm0 ----------------
__global__ __launch_bounds__(256) void init_kernel(
        const float* __restrict__ x,
        const float* __restrict__ W_node, const float* __restrict__ b_node,
        const float* __restrict__ Wm0, const float* __restrict__ bm0,
        float* __restrict__ h, float* __restrict__ hm)
{
    int n = blockIdx.x * blockDim.x + threadIdx.x;
    if (n >= NN) return;

    float xin[DN];
    #pragma unroll
    for (int k = 0; k < DN/4; ++k) {
        float4 v = ((const float4*)(x + (long)n*DN))[k];
        xin[4*k+0]=v.x; xin[4*k+1]=v.y; xin[4*k+2]=v.z; xin[4*k+3]=v.w;
    }
    float hv[H];
    #pragma unroll
    for (int j = 0; j < H; ++j) hv[j] = b_node[j];
    #pragma unroll
    for (int k = 0; k < DN; ++k)
        #pragma unroll
        for (int j = 0; j < H; ++j)
            hv[j] = fmaf(xin[k], W_node[k*H+j], hv[j]);

    #pragma unroll
    for (int j = 0; j < H/4; ++j)
        ((float4*)(h + (long)n*H))[j] = make_float4(hv[4*j],hv[4*j+1],hv[4*j+2],hv[4*j+3]);

    float hmv[H];
    #pragma unroll
    for (int j = 0; j < H; ++j) hmv[j] = bm0[j];
    #pragma unroll
    for (int k = 0; k < H; ++k)
        #pragma unroll
        for (int j = 0; j < H; ++j)
            hmv[j] = fmaf(hv[k], Wm0[k*H+j], hmv[j]);

    #pragma unroll
    for (int j = 0; j < H/4; ++j)
        ((float4*)(hm + (long)n*H))[j] = make_float4(hmv[4*j],hmv[4*j+1],hmv[4*j+2],hmv[4*j+3]);
}

// per-edge message + max, shared by all aggr paths
#define MSG_FMA(A, B, M0, M1)                                         \
    M0 = fmaf(A.x, w0[0], M0);  M1 = fmaf(A.x, w1[0], M1);            \
    M0 = fmaf(A.y, w0[1], M0);  M1 = fmaf(A.y, w1[1], M1);            \
    M0 = fmaf(A.z, w0[2], M0);  M1 = fmaf(A.z, w1[2], M1);            \
    M0 = fmaf(A.w, w0[3], M0);  M1 = fmaf(A.w, w1[3], M1);            \
    M0 = fmaf(B.x, w0[4], M0);  M1 = fmaf(B.x, w1[4], M1);            \
    M0 = fmaf(B.y, w0[5], M0);  M1 = fmaf(B.y, w1[5], M1);            \
    M0 = fmaf(B.z, w0[6], M0);  M1 = fmaf(B.z, w1[6], M1);            \
    M0 = fmaf(B.w, w0[7], M0);  M1 = fmaf(B.w, w1[7], M1);

// ---------------- per-layer aggregation: CSR gather-max, unroll-4 ----------
__global__ __launch_bounds__(256) void aggr_kernel(
        const int* __restrict__ rowstart, const int* __restrict__ es,
        const float* __restrict__ eas,      // [E][DE] dst-sorted
        const float* __restrict__ Wm_bot,   // [DE][H]
        const float* __restrict__ hm,
        float* __restrict__ aggr)
{
    int tid  = blockIdx.x * blockDim.x + threadIdx.x;
    int node = tid >> 4;
    int sub  = tid & 15;
    if (node >= NN) return;

    float w0[DE], w1[DE];
    #pragma unroll
    for (int k = 0; k < DE; ++k) {
        w0[k] = Wm_bot[k*H + sub*2 + 0];
        w1[k] = Wm_bot[k*H + sub*2 + 1];
    }

    float acc0 = -__builtin_inff(), acc1 = -__builtin_inff();

    int lo = rowstart[node], hi = rowstart[node+1];
    int i = lo;

    for (; i + 3 < hi; i += 4) {
        int s0 = es[i], s1 = es[i+1], s2 = es[i+2], s3 = es[i+3];
        float2 hv0 = *(const float2*)(hm + (long)s0*H + sub*2);
        float2 hv1 = *(const float2*)(hm + (long)s1*H + sub*2);
        float2 hv2 = *(const float2*)(hm + (long)s2*H + sub*2);
        float2 hv3 = *(const float2*)(hm + (long)s3*H + sub*2);
        const float4* p0 = (const float4*)(eas + (long)i * DE);
        const float4* p1 = (const float4*)(eas + (long)(i+1) * DE);
        const float4* p2 = (const float4*)(eas + (long)(i+2) * DE);
        const float4* p3 = (const float4*)(eas + (long)(i+3) * DE);
        float4 a0 = p0[0], b0 = p0[1];
        float4 a1 = p1[0], b1 = p1[1];
        float4 a2 = p2[0], b2 = p2[1];
        float4 a3 = p3[0], b3 = p3[1];
        float m00 = hv0.x, m01 = hv0.y;
        float m10 = hv1.x, m11 = hv1.y;
        float m20 = hv2.x, m21 = hv2.y;
        float m30 = hv3.x, m31 = hv3.y;
        MSG_FMA(a0, b0, m00, m01)
        MSG_FMA(a1, b1, m10, m11)
        MSG_FMA(a2, b2, m20, m21)
        MSG_FMA(a3, b3, m30, m31)
        acc0 = fmaxf(acc0, fmaxf(fmaxf(m00, m10), fmaxf(m20, m30)));
        acc1 = fmaxf(acc1, fmaxf(fmaxf(m01, m11), fmaxf(m21, m31)));
    }
    for (; i + 1 < hi; i += 2) {
        int s0 = es[i], s1 = es[i+1];
        float2 hv0 = *(const float2*)(hm + (long)s0*H + sub*2);
        float2 hv1 = *(const float2*)(hm + (long)s1*H + sub*2);
        const float4* p0 = (const float4*)(eas + (long)i * DE);
        const float4* p1 = (const float4*)(eas + (long)(i+1) * DE);
        float4 a0 = p0[0], b0 = p0[1];
        float4 a1 = p1[0], b1 = p1[1];
        float m00 = hv0.x, m01 = hv0.y;
        float m10 = hv1.x, m11 = hv1.y;
        MSG_FMA(a0, b0, m00, m01)
        MSG_FMA(a1, b1, m10, m11)
        acc0 = fmaxf(acc0, fmaxf(m00, m10));
        acc1 = fmaxf(acc1, fmaxf(m01, m11));
    }
    if (i < hi) {
        int s0 = es[i];
        float2 hv0 = *(const float2*)(hm + (long)s0*H + sub*2);
        const float4* p0 = (const float4*)(eas + (long)i * DE);
        float4 a0 = p0[0], b0 = p0[1];
        float m00 = hv0.x, m01 = hv0.y;
        MSG_FMA(a0, b0, m00, m01)
        acc0 = fmaxf(acc0, m00);
        acc1 = fmaxf(acc1, m01);
    }
    if (lo == hi) { acc0 = 0.f; acc1 = 0.f; }
    *(float2*)(aggr + (long)node*H + sub*2) = make_float2(acc0, acc1);
}

// ---------------- node update: relu(aggr@Wu+bu) + residual ; next hm or post ----------------
__global__ __launch_bounds__(256) void update_kernel(
        const float* __restrict__ Wu, const float* __restrict__ bu,
        const float* __restrict__ Wm_next, const float* __restrict__ bm_next, // null if last
        const float* __restrict__ W_post, const float* __restrict__ b_post,   // used if last
        float* __restrict__ h, float* __restrict__ hm,
        const float* __restrict__ aggr, float* __restrict__ out, int last)
{
    int n = blockIdx.x * blockDim.x + threadIdx.x;
    if (n >= NN) return;

    float av[H];
    #pragma unroll
    for (int j = 0; j < H/4; ++j) {
        float4 v = ((const float4*)(aggr + (long)n*H))[j];
        av[4*j+0]=v.x; av[4*j+1]=v.y; av[4*j+2]=v.z; av[4*j+3]=v.w;
    }

    float uv[H];
    #pragma unroll
    for (int j = 0; j < H; ++j) uv[j] = bu[j];
    #pragma unroll
    for (int k = 0; k < H; ++k)
        #pragma unroll
        for (int j = 0; j < H; ++j)
            uv[j] = fmaf(av[k], Wu[k*H+j], uv[j]);

    float hv[H];
    #pragma unroll
    for (int j = 0; j < H/4; ++j) {
        float4 v = ((const float4*)(h + (long)n*H))[j];
        hv[4*j+0]=v.x; hv[4*j+1]=v.y; hv[4*j+2]=v.z; hv[4*j+3]=v.w;
    }
    #pragma unroll
    for (int j = 0; j < H; ++j) hv[j] += fmaxf(uv[j], 0.f);

    #pragma unroll
    for (int j = 0; j < H/4; ++j)
        ((float4*)(h + (long)n*H))[j] = make_float4(hv[4*j],hv[4*j+1],hv[4*j+2],hv[4*j+3]);

    if (!last) {
        float hmv[H];
        #pragma unroll
        for (int j = 0; j < H; ++j) hmv[j] = bm_next[j];
        #pragma unroll
        for (int k = 0; k < H; ++k)
            #pragma unroll
            for (int j = 0; j < H; ++j)
                hmv[j] = fmaf(hv[k], Wm_next[k*H+j], hmv[j]);
        #pragma unroll
        for (int j = 0; j < H/4; ++j)
            ((float4*)(hm + (long)n*H))[j] = make_float4(hmv[4*j],hmv[4*j+1],hmv[4*j+2],hmv[4*j+3]);
    } else {
        float acc = b_post[0];
        #pragma unroll
        for (int k = 0; k < H; ++k) acc = fmaf(hv[k], W_post[k], acc);
        out[n] = acc;
    }
}

extern "C" void kernel_launch(void* const* d_in, const int* in_sizes, int n_in,
                              void* d_out, int out_size, void* d_ws, size_t ws_size,
                              hipStream_t stream)
{
    const float* x         = (const float*)d_in[0];
    const float* edge_attr = (const float*)d_in[1];
    const int*   edge_index= (const int*)  d_in[2];
    const float* W_node    = (const float*)d_in[3];
    const float* b_node    = (const float*)d_in[4];
    const float* Wm        = (const float*)d_in[5];   // [L][H+DE][H]
    const float* bm        = (const float*)d_in[6];   // [L][H]
    const float* Wu        = (const float*)d_in[7];   // [L][H][H]
    const float* bu        = (const float*)d_in[8];   // [L][H]
    const float* W_post    = (const float*)d_in[9];   // [H][1]
    const float* b_post    = (const float*)d_in[10];  // [1]
    float* out = (float*)d_out;

    const int* src = edge_index;        // row 0 (x_j source)
    const int* dst = edge_index + NE;   // row 1 (aggregation target)

    // workspace layout (all 16B-aligned); total ~110.6 MB
    char* ws = (char*)d_ws;
    size_t off = 0;
    float* h        = (float*)(ws + off); off += (size_t)NN*H*4;        // 12.8 MB
    float* hm       = (float*)(ws + off); off += (size_t)NN*H*4;        // 12.8 MB
    float* aggr     = (float*)(ws + off); off += (size_t)NN*H*4;        // 12.8 MB
    int*   rowstart = (int*)  (ws + off); off += (size_t)(NN+16)*4;     // 0.4 MB
    int*   es       = (int*)  (ws + off); off += (size_t)NE*4;          // 6.4 MB
    float* eas      = (float*)(ws + off); off += (size_t)NE*DE*4;       // 51.2 MB
    int2*  ebkt     = (int2*) (ws + off); off += (size_t)NE*8;          // 12.8 MB
    int*   gcountsT = (int*)  (ws + off); off += (size_t)GCN*4;         // 0.8 MB
    int*   gbaseT   = (int*)  (ws + off); off += (size_t)GCN*4;         // 0.8 MB
    int*   bsum2    = (int*)  (ws + off); off += (size_t)G_BT*4;
    int*   boff2    = (int*)  (ws + off); off += (size_t)G_BT*4;

    const int nodeBlocks = (NN + 255) / 256;
    const int aggrBlocks = (NN*16 + 255) / 256;

    // ---- build CSR: two-level LDS counting sort, zero global atomics ----
    coarse_hist_kernel   <<<CBLK, 256, 0, stream>>>(dst, gcountsT);
    scanG_partial_kernel <<<G_NB, G_BT, 0, stream>>>(gcountsT, bsum2);
    scanG_bsum_kernel    <<<1, G_BSUM_T, 0, stream>>>(bsum2, boff2);
    scanG_final_kernel   <<<G_NB, G_BT, 0, stream>>>(gcountsT, boff2, gbaseT);
    coarse_scatter_kernel<<<CBLK, 256, 0, stream>>>(dst, gbaseT, ebkt);
    fine_sort_kernel     <<<NBKT, 256, 0, stream>>>(ebkt, gbaseT, src, edge_attr,
                                                    rowstart, es, eas);

    // ---- node init ----
    init_kernel<<<nodeBlocks, 256, 0, stream>>>(x, W_node, b_node, Wm, bm, h, hm);

    // ---- layers ----
    for (int l = 0; l < NL; ++l) {
        const float* Wm_l   = Wm + (size_t)l*(H+DE)*H;
        const float* Wm_bot = Wm_l + (size_t)H*H;        // rows 32..39 multiply edge_attr
        const float* Wu_l   = Wu + (size_t)l*H*H;
        const float* bu_l   = bu + (size_t)l*H;
        int last = (l == NL-1);
        const float* Wm_next = last ? nullptr : Wm + (size_t)(l+1)*(H+DE)*H;
        const float* bm_next = last ? nullptr : bm + (size_t)(l+1)*H;

        aggr_kernel<<<aggrBlocks, 256, 0, stream>>>(rowstart, es, eas, Wm_bot, hm, aggr);
        update_kernel<<<nodeBlocks, 256, 0, stream>>>(Wu_l, bu_l, Wm_next, bm_next,
                                                      W_post, b_post, h, hm, aggr, out, last);
    }
}